// Round 24
// baseline (375.182 us; speedup 1.0000x reference)
//
#include <hip/hip_runtime.h>
#include <hip/hip_fp16.h>

constexpr int H_  = 64;   // hidden
constexpr int DIN = 32;   // atom feature dim
constexpr int DE  = 16;   // edge feature dim
constexpr int BNODE = 512;  // nodes per scatter bucket (dstlocal < 512)
constexpr int ACH   = 2048; // edges per binning chunk
constexpr int CAP   = 6144; // per-bucket bin region capacity (mean 5120 + 14 sigma)
constexpr int CAP2  = CAP + BNODE; // per-bucket rec region (edges + self-loops)
#define SLOPE 0.2f

typedef __attribute__((ext_vector_type(8))) short bf16x8;
typedef __attribute__((ext_vector_type(4))) float f32x4;

__device__ __forceinline__ float sigm_(float x){ return 1.0f/(1.0f+__expf(-x)); }
__device__ __forceinline__ float tanh_(float x){ float e=__expf(2.0f*x); return 1.0f - 2.0f/(e+1.0f); }
__device__ __forceinline__ short f2bf(float f){   // RNE float->bf16
  unsigned u = __float_as_uint(f);
  u += 0x7FFF + ((u>>16)&1);
  return (short)(u>>16);
}
__device__ __forceinline__ float bf2f(unsigned short s){
  return __uint_as_float(((unsigned)s)<<16);
}
__device__ __forceinline__ float h2f_(unsigned hb){
  return __half2float(__ushort_as_half((unsigned short)hb));
}

// mega-kernel: weight prep + bcur init + graph bounds
__global__ void k_prep(const float* __restrict__ w_node, const float* __restrict__ w_edge,
                       const float* __restrict__ b_edge,
                       const float* __restrict__ conv_W, const float* __restrict__ gWih,
                       const float* __restrict__ gWhh, const float* __restrict__ conv_We,
                       const float* __restrict__ att_e, const int* __restrict__ batch,
                       short* __restrict__ wnT16, short* __restrict__ weT16p,
                       short* __restrict__ cWT16, short* __restrict__ WihT16,
                       short* __restrict__ WhhT16, float* __restrict__ ve,
                       int* __restrict__ bcur, int* __restrict__ gstart, int N, int G){
  int id = blockIdx.x*blockDim.x + threadIdx.x;
  if (id < 2048){                                   // wnT16 [64][32]
    int j = id >> 5, k = id & 31;
    wnT16[id] = f2bf(w_node[k*64 + j]);
    return;
  }
  id -= 2048;
  if (id < 2048){                                   // weT16p [64][32]; k=16 row = bias
    int j = id >> 5, k = id & 31;
    weT16p[id] = (k < DE) ? f2bf(w_edge[k*64 + j]) : (k == DE ? f2bf(b_edge[j]) : (short)0);
    return;
  }
  id -= 2048;
  if (id < 12288){                                  // cWT16 [3][64 j][64 k]
    int l = id / 4096, rem = id & 4095, j = rem >> 6, k = rem & 63;
    cWT16[id] = f2bf(conv_W[l*4096 + k*64 + j]);
    return;
  }
  id -= 12288;
  if (id < 36864){                                  // WihT16 [3][192 j][64 k]
    int l = id / 12288, rem = id % 12288, j = rem >> 6, k = rem & 63;
    WihT16[id] = f2bf(gWih[l*12288 + k*192 + j]);
    return;
  }
  id -= 36864;
  if (id < 36864){                                  // WhhT16
    int l = id / 12288, rem = id % 12288, j = rem >> 6, k = rem & 63;
    WhhT16[id] = f2bf(gWhh[l*12288 + k*192 + j]);
    return;
  }
  id -= 36864;
  if (id < 192){                                    // ve[l][k]
    int l = id >> 6, k = id & 63;
    const float* w = conv_We + (size_t)(l*64+k)*64;
    const float* a = att_e + l*64;
    float s = 0.f;
    #pragma unroll
    for (int j=0;j<64;j++) s += w[j]*a[j];
    ve[id] = s;
    return;
  }
  id -= 192;
  if (id < 256){ bcur[id] = id*CAP; return; }       // fixed-capacity bin regions
  id -= 256;
  if (id < N){                                      // graph bounds (sorted batch)
    int b = batch[id];
    int bp = (id==0) ? -1 : batch[id-1];
    for (int g=bp+1; g<=b; g++) gstart[g]=id;
    if (id==N-1){ for (int g=b+1; g<=G; g++) gstart[g]=N; }
  }
}

// MFMA node MLP: xi16 = bf16(relu(x @ w_node + b)), K=32 exact. No LDS.
__global__ void __launch_bounds__(256,4)
k_nmlp_m(const float* __restrict__ x, const short* __restrict__ wT16,
         const float* __restrict__ b, short* __restrict__ xi, int N){
  int lane = threadIdx.x & 63, w = threadIdx.x >> 6;
  int m16 = lane & 15, kb = lane >> 4;
  int n0 = blockIdx.x*64 + w*16;
  int arow = n0 + m16; if (arow > N-1) arow = N-1;
  const float* xr = x + (size_t)arow*DIN + kb*8;
  float4 a0 = *(const float4*)xr, a1 = *(const float4*)(xr+4);
  bf16x8 af;
  af[0]=f2bf(a0.x); af[1]=f2bf(a0.y); af[2]=f2bf(a0.z); af[3]=f2bf(a0.w);
  af[4]=f2bf(a1.x); af[5]=f2bf(a1.y); af[6]=f2bf(a1.z); af[7]=f2bf(a1.w);
  f32x4 acc[4];
  #pragma unroll
  for (int t=0;t<4;t++) acc[t]=(f32x4){0.f,0.f,0.f,0.f};
  const short* wp = wT16 + (size_t)m16*DIN + kb*8;
  #pragma unroll
  for (int t=0;t<4;t++){
    bf16x8 bb = *(const bf16x8*)(wp + (size_t)(t*16)*DIN);
    acc[t] = __builtin_amdgcn_mfma_f32_16x16x32_bf16(af, bb, acc[t], 0,0,0);
  }
  int mrow = (lane>>4)*4;
  #pragma unroll
  for (int t=0;t<4;t++){
    int f = t*16 + m16;
    float bj = b[f];
    #pragma unroll
    for (int q=0;q<4;q++){
      int node = n0 + mrow + q;
      if (node < N) xi[(size_t)node*H_ + f] = f2bf(fmaxf(acc[t][q] + bj, 0.f));
    }
  }
}

// Transposed MFMA edge scores: D = W^T @ attr^T so each lane holds 16 j-values of ONE
// edge -> ve-dot is lane-local; reduce is only over the 4 kb groups (2 shfl steps).
__global__ void __launch_bounds__(256,4)
k_edge_m(const float* __restrict__ attr, const short* __restrict__ weT16p,
         const float* __restrict__ ve, const int* __restrict__ src,
         uint2* __restrict__ esc8, int E){
  int lane = threadIdx.x & 63, w = threadIdx.x >> 6;
  int m16 = lane & 15, kb = lane >> 4;
  int e0 = (blockIdx.x*4 + w)*32;        // 2 tiles of 16 edges
  if (e0 >= E) return;
  const short* wp = weT16p + (size_t)m16*32 + kb*8;
  bf16x8 wA0 = *(const bf16x8*)(wp);
  bf16x8 wA1 = *(const bf16x8*)(wp + 16*32);
  bf16x8 wA2 = *(const bf16x8*)(wp + 32*32);
  bf16x8 wA3 = *(const bf16x8*)(wp + 48*32);
  bf16x8 af0 = {0,0,0,0,0,0,0,0}, af1 = {0,0,0,0,0,0,0,0};
  if (kb < 2){
    int r0 = e0 + m16;      if (r0 > E-1) r0 = E-1;
    int r1 = e0 + 16 + m16; if (r1 > E-1) r1 = E-1;
    const float* ap0 = attr + (size_t)r0*DE + kb*8;
    const float* ap1 = attr + (size_t)r1*DE + kb*8;
    float4 a0 = *(const float4*)ap0, a1 = *(const float4*)(ap0+4);
    float4 b0 = *(const float4*)ap1, b1 = *(const float4*)(ap1+4);
    af0[0]=f2bf(a0.x); af0[1]=f2bf(a0.y); af0[2]=f2bf(a0.z); af0[3]=f2bf(a0.w);
    af0[4]=f2bf(a1.x); af0[5]=f2bf(a1.y); af0[6]=f2bf(a1.z); af0[7]=f2bf(a1.w);
    af1[0]=f2bf(b0.x); af1[1]=f2bf(b0.y); af1[2]=f2bf(b0.z); af1[3]=f2bf(b0.w);
    af1[4]=f2bf(b1.x); af1[5]=f2bf(b1.y); af1[6]=f2bf(b1.z); af1[7]=f2bf(b1.w);
  } else if (kb == 2){
    af0[0] = (short)0x3F80; af1[0] = (short)0x3F80;
  }
  f32x4 accA[4], accB[4];
  #pragma unroll
  for (int t=0;t<4;t++){ accA[t]=(f32x4){0.f,0.f,0.f,0.f}; accB[t]=(f32x4){0.f,0.f,0.f,0.f}; }
  accA[0] = __builtin_amdgcn_mfma_f32_16x16x32_bf16(wA0, af0, accA[0], 0,0,0);
  accB[0] = __builtin_amdgcn_mfma_f32_16x16x32_bf16(wA0, af1, accB[0], 0,0,0);
  accA[1] = __builtin_amdgcn_mfma_f32_16x16x32_bf16(wA1, af0, accA[1], 0,0,0);
  accB[1] = __builtin_amdgcn_mfma_f32_16x16x32_bf16(wA1, af1, accB[1], 0,0,0);
  accA[2] = __builtin_amdgcn_mfma_f32_16x16x32_bf16(wA2, af0, accA[2], 0,0,0);
  accB[2] = __builtin_amdgcn_mfma_f32_16x16x32_bf16(wA2, af1, accB[2], 0,0,0);
  accA[3] = __builtin_amdgcn_mfma_f32_16x16x32_bf16(wA3, af0, accA[3], 0,0,0);
  accB[3] = __builtin_amdgcn_mfma_f32_16x16x32_bf16(wA3, af1, accB[3], 0,0,0);

  int kb4 = kb*4;
  float sA0=0.f,sA1=0.f,sA2=0.f, sB0=0.f,sB1=0.f,sB2=0.f;
  #pragma unroll
  for (int t=0;t<4;t++){
    float4 v0 = *(const float4*)(ve + t*16 + kb4);
    float4 v1 = *(const float4*)(ve + 64 + t*16 + kb4);
    float4 v2 = *(const float4*)(ve + 128 + t*16 + kb4);
    float eA0 = fmaxf(accA[t][0],0.f), eA1 = fmaxf(accA[t][1],0.f);
    float eA2 = fmaxf(accA[t][2],0.f), eA3 = fmaxf(accA[t][3],0.f);
    float eB0 = fmaxf(accB[t][0],0.f), eB1 = fmaxf(accB[t][1],0.f);
    float eB2 = fmaxf(accB[t][2],0.f), eB3 = fmaxf(accB[t][3],0.f);
    sA0 = fmaf(eA0,v0.x, fmaf(eA1,v0.y, fmaf(eA2,v0.z, fmaf(eA3,v0.w, sA0))));
    sA1 = fmaf(eA0,v1.x, fmaf(eA1,v1.y, fmaf(eA2,v1.z, fmaf(eA3,v1.w, sA1))));
    sA2 = fmaf(eA0,v2.x, fmaf(eA1,v2.y, fmaf(eA2,v2.z, fmaf(eA3,v2.w, sA2))));
    sB0 = fmaf(eB0,v0.x, fmaf(eB1,v0.y, fmaf(eB2,v0.z, fmaf(eB3,v0.w, sB0))));
    sB1 = fmaf(eB0,v1.x, fmaf(eB1,v1.y, fmaf(eB2,v1.z, fmaf(eB3,v1.w, sB1))));
    sB2 = fmaf(eB0,v2.x, fmaf(eB1,v2.y, fmaf(eB2,v2.z, fmaf(eB3,v2.w, sB2))));
  }
  sA0 += __shfl_xor(sA0,16); sA0 += __shfl_xor(sA0,32);
  sA1 += __shfl_xor(sA1,16); sA1 += __shfl_xor(sA1,32);
  sA2 += __shfl_xor(sA2,16); sA2 += __shfl_xor(sA2,32);
  sB0 += __shfl_xor(sB0,16); sB0 += __shfl_xor(sB0,32);
  sB1 += __shfl_xor(sB1,16); sB1 += __shfl_xor(sB1,32);
  sB2 += __shfl_xor(sB2,16); sB2 += __shfl_xor(sB2,32);
  if (lane < 16){
    int eA = e0 + lane;
    if (eA < E){
      unsigned sv = (unsigned)src[eA];
      unsigned h0 = (__half_as_ushort(__float2half(sA0)) & 0xFFFEu) | (sv >> 16);
      unsigned h1 = __half_as_ushort(__float2half(sA1));
      unsigned h2 = __half_as_ushort(__float2half(sA2));
      esc8[eA] = make_uint2(h0 | (h1<<16), (sv & 0xFFFFu) | (h2<<16));
    }
    int eB = e0 + 16 + lane;
    if (eB < E){
      unsigned sv = (unsigned)src[eB];
      unsigned h0 = (__half_as_ushort(__float2half(sB0)) & 0xFFFEu) | (sv >> 16);
      unsigned h1 = __half_as_ushort(__float2half(sB1));
      unsigned h2 = __half_as_ushort(__float2half(sB2));
      esc8[eB] = make_uint2(h0 | (h1<<16), (sv & 0xFFFFu) | (h2<<16));
    }
  }
}

// pass A: LDS-binned append of 8B records + 2B dstlocal into fixed per-bucket regions.
__global__ void __launch_bounds__(256)
k_binA(const uint2* __restrict__ esc8, const int* __restrict__ dst,
       int* __restrict__ bcur, uint2* __restrict__ bin8, unsigned short* __restrict__ bin2,
       int E){
  __shared__ int cnt[256];
  __shared__ int ofs[256];
  __shared__ int gofs[256];
  __shared__ uint2 st8[ACH];
  __shared__ unsigned short st2[ACH];
  __shared__ unsigned char sbid[ACH];
  int tid = threadIdx.x;
  int base = blockIdx.x * ACH;
  cnt[tid] = 0;
  __syncthreads();
  uint2 r8[8]; int bb[8]; int ms[8]; int dl[8];
  #pragma unroll
  for (int k=0;k<8;k++){
    int e = base + tid + k*256;
    bb[k] = -1;
    if (e < E){
      r8[k] = esc8[e];
      int d = dst[e];
      bb[k] = d >> 9;
      dl[k] = d & (BNODE-1);
      ms[k] = atomicAdd(&cnt[bb[k]], 1);
    }
  }
  __syncthreads();
  int v = cnt[tid];
  ofs[tid] = v;
  __syncthreads();
  for (int d=1; d<256; d<<=1){
    int t = 0;
    if (tid>=d) t = ofs[tid-d];
    __syncthreads();
    if (tid>=d) ofs[tid] += t;
    __syncthreads();
  }
  int total = ofs[255];
  int excl = ofs[tid] - v;
  __syncthreads();
  ofs[tid] = excl;
  __syncthreads();
  #pragma unroll
  for (int k=0;k<8;k++){
    if (bb[k] >= 0){
      int slot = ofs[bb[k]] + ms[k];
      st8[slot] = r8[k];
      st2[slot] = (unsigned short)dl[k];
      sbid[slot] = (unsigned char)bb[k];
    }
  }
  if (v > 0) gofs[tid] = atomicAdd(&bcur[tid], v);
  __syncthreads();
  for (int slot = tid; slot < total; slot += 256){
    int b = sbid[slot];
    int gp = gofs[b] + (slot - ofs[b]);
    bin8[gp] = st8[slot];
    bin2[gp] = st2[slot];
  }
}

// fused pass B: per bucket = histogram -> LDS scan -> offS/offE -> scatter (+LDS score
// sums) -> self-loop records. Zero global atomics, no global scan kernels.
__global__ void __launch_bounds__(256)
k_binB2(const uint2* __restrict__ bin8, const unsigned short* __restrict__ bin2,
        const int* __restrict__ bcur, int* __restrict__ offS, int* __restrict__ offE,
        uint2* __restrict__ rec, int N){
  __shared__ int lcnt[BNODE];
  __shared__ int lcur[BNODE];
  __shared__ int loffS[BNODE];
  __shared__ int sc[256];
  __shared__ float ls0[BNODE], ls1[BNODE], ls2[BNODE];
  int b = blockIdx.x, tid = threadIdx.x;
  int n0 = b*BNODE;
  int n1 = n0 + BNODE; if (n1 > N) n1 = N;
  int nn = n1 - n0;
  for (int i=tid;i<BNODE;i+=256){ lcnt[i]=0; ls0[i]=0.f; ls1[i]=0.f; ls2[i]=0.f; }
  __syncthreads();
  int beg = b*CAP, cntb = bcur[b] - beg;
  for (int idx=tid; idx<cntb; idx+=256) atomicAdd(&lcnt[bin2[beg+idx]], 1);
  __syncthreads();
  int i0 = 2*tid, i1 = 2*tid+1;
  int a0 = (i0<nn) ? lcnt[i0]+1 : 0;
  int a1 = (i1<nn) ? lcnt[i1]+1 : 0;
  int pair = a0+a1;
  sc[tid] = pair;
  __syncthreads();
  for (int d=1; d<256; d<<=1){
    int t = 0; if (tid>=d) t = sc[tid-d];
    __syncthreads();
    if (tid>=d) sc[tid] += t;
    __syncthreads();
  }
  int excl = sc[tid] - pair;
  int base = b*CAP2;
  if (i0<nn){ int o=base+excl;    offS[n0+i0]=o; offE[n0+i0]=o+a0; loffS[i0]=o; lcur[i0]=o+1; }
  if (i1<nn){ int o=base+excl+a0; offS[n0+i1]=o; offE[n0+i1]=o+a1; loffS[i1]=o; lcur[i1]=o+1; }
  __syncthreads();
  for (int idx=tid; idx<cntb; idx+=256){
    uint2 r = bin8[beg+idx];
    int dl = bin2[beg+idx];
    int p = atomicAdd(&lcur[dl], 1);
    rec[p] = r;
    atomicAdd(&ls0[dl], h2f_(r.x & 0xFFFEu));
    atomicAdd(&ls1[dl], h2f_(r.x >> 16));
    atomicAdd(&ls2[dl], h2f_(r.y >> 16));
  }
  __syncthreads();
  for (int i=tid; i<nn; i+=256){
    int cnt = lcnt[i];
    float inv = (cnt>0) ? 1.0f/(float)cnt : 0.0f;
    unsigned h0 = __half_as_ushort(__float2half(ls0[i]*inv)) & 0xFFFEu;
    unsigned h1 = __half_as_ushort(__float2half(ls1[i]*inv));
    unsigned h2 = __half_as_ushort(__float2half(ls2[i]*inv));
    unsigned s = (unsigned)(n0+i);
    rec[loffS[i]] = make_uint2(h0 | (s>>16) | (h1<<16), (s & 0xFFFFu) | (h2<<16));
  }
}

// MFMA GRU: 2 strips/wave, per-tile gate compute (8 live acc), LDS output staging
// -> strided gate writes hit LDS (free), global stores are coalesced full rows.
__global__ void __launch_bounds__(256,4)
k_gru_m(const short* __restrict__ hg16, const short* __restrict__ xin, short* __restrict__ xout,
        const short* __restrict__ WihT16, const short* __restrict__ WhhT16,
        const float* __restrict__ bih, const float* __restrict__ bhh, int N){
  __shared__ unsigned short sOut[4][32][68];   // stride 68 shorts: 2-bank rotation/row
  int lane = threadIdx.x & 63, w = threadIdx.x >> 6;
  int m16 = lane & 15;
  int kb  = lane >> 4;
  int n0 = blockIdx.x*128 + w*32;

  int r0 = n0 + m16;      if (r0 > N-1) r0 = N-1;
  int r1 = n0 + 16 + m16; if (r1 > N-1) r1 = N-1;
  const short* h0p = hg16 + (size_t)r0*H_ + kb*8;
  const short* h1p = hg16 + (size_t)r1*H_ + kb*8;
  bf16x8 ah0a = *(const bf16x8*)(h0p), ah1a = *(const bf16x8*)(h0p+32);
  bf16x8 ah0b = *(const bf16x8*)(h1p), ah1b = *(const bf16x8*)(h1p+32);
  const short* x0p = xin + (size_t)r0*H_ + kb*8;
  const short* x1p = xin + (size_t)r1*H_ + kb*8;
  bf16x8 ax0a = *(const bf16x8*)(x0p), ax1a = *(const bf16x8*)(x0p+32);
  bf16x8 ax0b = *(const bf16x8*)(x1p), ax1b = *(const bf16x8*)(x1p+32);

  const short* wi = WihT16 + (size_t)m16*H_ + kb*8;
  const short* wh = WhhT16 + (size_t)m16*H_ + kb*8;
  int mrow = kb*4;

  #pragma unroll
  for (int t=0;t<4;t++){
    f32x4 aR0=(f32x4){0.f,0.f,0.f,0.f}, aR1=(f32x4){0.f,0.f,0.f,0.f};
    f32x4 aZ0=(f32x4){0.f,0.f,0.f,0.f}, aZ1=(f32x4){0.f,0.f,0.f,0.f};
    f32x4 aNi0=(f32x4){0.f,0.f,0.f,0.f}, aNi1=(f32x4){0.f,0.f,0.f,0.f};
    f32x4 aNh0=(f32x4){0.f,0.f,0.f,0.f}, aNh1=(f32x4){0.f,0.f,0.f,0.f};
    bf16x8 b;
    b = *(const bf16x8*)(wi + (size_t)(t*16)*H_);
    aR0 = __builtin_amdgcn_mfma_f32_16x16x32_bf16(ah0a, b, aR0, 0,0,0);
    aR1 = __builtin_amdgcn_mfma_f32_16x16x32_bf16(ah0b, b, aR1, 0,0,0);
    b = *(const bf16x8*)(wi + (size_t)(t*16)*H_ + 32);
    aR0 = __builtin_amdgcn_mfma_f32_16x16x32_bf16(ah1a, b, aR0, 0,0,0);
    aR1 = __builtin_amdgcn_mfma_f32_16x16x32_bf16(ah1b, b, aR1, 0,0,0);
    b = *(const bf16x8*)(wh + (size_t)(t*16)*H_);
    aR0 = __builtin_amdgcn_mfma_f32_16x16x32_bf16(ax0a, b, aR0, 0,0,0);
    aR1 = __builtin_amdgcn_mfma_f32_16x16x32_bf16(ax0b, b, aR1, 0,0,0);
    b = *(const bf16x8*)(wh + (size_t)(t*16)*H_ + 32);
    aR0 = __builtin_amdgcn_mfma_f32_16x16x32_bf16(ax1a, b, aR0, 0,0,0);
    aR1 = __builtin_amdgcn_mfma_f32_16x16x32_bf16(ax1b, b, aR1, 0,0,0);

    b = *(const bf16x8*)(wi + (size_t)(64+t*16)*H_);
    aZ0 = __builtin_amdgcn_mfma_f32_16x16x32_bf16(ah0a, b, aZ0, 0,0,0);
    aZ1 = __builtin_amdgcn_mfma_f32_16x16x32_bf16(ah0b, b, aZ1, 0,0,0);
    b = *(const bf16x8*)(wi + (size_t)(64+t*16)*H_ + 32);
    aZ0 = __builtin_amdgcn_mfma_f32_16x16x32_bf16(ah1a, b, aZ0, 0,0,0);
    aZ1 = __builtin_amdgcn_mfma_f32_16x16x32_bf16(ah1b, b, aZ1, 0,0,0);
    b = *(const bf16x8*)(wh + (size_t)(64+t*16)*H_);
    aZ0 = __builtin_amdgcn_mfma_f32_16x16x32_bf16(ax0a, b, aZ0, 0,0,0);
    aZ1 = __builtin_amdgcn_mfma_f32_16x16x32_bf16(ax0b, b, aZ1, 0,0,0);
    b = *(const bf16x8*)(wh + (size_t)(64+t*16)*H_ + 32);
    aZ0 = __builtin_amdgcn_mfma_f32_16x16x32_bf16(ax1a, b, aZ0, 0,0,0);
    aZ1 = __builtin_amdgcn_mfma_f32_16x16x32_bf16(ax1b, b, aZ1, 0,0,0);

    b = *(const bf16x8*)(wi + (size_t)(128+t*16)*H_);
    aNi0 = __builtin_amdgcn_mfma_f32_16x16x32_bf16(ah0a, b, aNi0, 0,0,0);
    aNi1 = __builtin_amdgcn_mfma_f32_16x16x32_bf16(ah0b, b, aNi1, 0,0,0);
    b = *(const bf16x8*)(wi + (size_t)(128+t*16)*H_ + 32);
    aNi0 = __builtin_amdgcn_mfma_f32_16x16x32_bf16(ah1a, b, aNi0, 0,0,0);
    aNi1 = __builtin_amdgcn_mfma_f32_16x16x32_bf16(ah1b, b, aNi1, 0,0,0);
    b = *(const bf16x8*)(wh + (size_t)(128+t*16)*H_);
    aNh0 = __builtin_amdgcn_mfma_f32_16x16x32_bf16(ax0a, b, aNh0, 0,0,0);
    aNh1 = __builtin_amdgcn_mfma_f32_16x16x32_bf16(ax0b, b, aNh1, 0,0,0);
    b = *(const bf16x8*)(wh + (size_t)(128+t*16)*H_ + 32);
    aNh0 = __builtin_amdgcn_mfma_f32_16x16x32_bf16(ax1a, b, aNh0, 0,0,0);
    aNh1 = __builtin_amdgcn_mfma_f32_16x16x32_bf16(ax1b, b, aNh1, 0,0,0);

    int f = t*16 + m16;
    float br = bih[f]     + bhh[f];
    float bz = bih[64+f]  + bhh[64+f];
    float bin= bih[128+f], bhn = bhh[128+f];
    #pragma unroll
    for (int q=0;q<4;q++){
      int node = n0 + mrow + q;  if (node > N-1) node = N-1;
      float r  = sigm_(aR0[q] + br);
      float z  = sigm_(aZ0[q] + bz);
      float nn = tanh_(aNi0[q] + bin + r*(aNh0[q] + bhn));
      float xv = bf2f((unsigned short)xin[(size_t)node*H_ + f]);
      sOut[w][mrow+q][f] = (unsigned short)f2bf(fmaxf((1.f-z)*nn + z*xv, 0.f));
    }
    #pragma unroll
    for (int q=0;q<4;q++){
      int node = n0 + 16 + mrow + q;  if (node > N-1) node = N-1;
      float r  = sigm_(aR1[q] + br);
      float z  = sigm_(aZ1[q] + bz);
      float nn = tanh_(aNi1[q] + bin + r*(aNh1[q] + bhn));
      float xv = bf2f((unsigned short)xin[(size_t)node*H_ + f]);
      sOut[w][16+mrow+q][f] = (unsigned short)f2bf(fmaxf((1.f-z)*nn + z*xv, 0.f));
    }
  }

  // coalesced store phase (wave-local LDS, no barrier needed)
  int row = lane >> 1, half = lane & 1;
  int node = n0 + row;
  if (node < N){
    short* gp = xout + (size_t)node*H_ + half*32;
    #pragma unroll
    for (int i=0;i<8;i++){
      *(uint2*)(gp + i*4) = *(const uint2*)&sOut[w][row][half*32 + i*4];
    }
  }
}

// MFMA linear-h: 2 node-strips per wave, LDS-staged h16 stores. bf16 input.
__global__ void __launch_bounds__(256,4)
k_linh_m(const short* __restrict__ xi, const short* __restrict__ wT16,
         const float* __restrict__ atts, const float* __restrict__ attd,
         __half* __restrict__ h16, float* __restrict__ ssc, float* __restrict__ dsc, int N){
  __shared__ unsigned short sH[4][32][68];
  int lane = threadIdx.x & 63, w = threadIdx.x >> 6;
  int m16 = lane & 15, kb = lane >> 4;
  int n0 = blockIdx.x*128 + w*32;
  int r0 = n0 + m16;      if (r0 > N-1) r0 = N-1;
  int r1 = n0 + 16 + m16; if (r1 > N-1) r1 = N-1;
  const short* x0p = xi + (size_t)r0*H_ + kb*8;
  const short* x1p = xi + (size_t)r1*H_ + kb*8;
  bf16x8 ax0a = *(const bf16x8*)(x0p), ax1a = *(const bf16x8*)(x0p+32);
  bf16x8 ax0b = *(const bf16x8*)(x1p), ax1b = *(const bf16x8*)(x1p+32);

  f32x4 acc[2][4];
  #pragma unroll
  for (int s=0;s<2;s++)
    #pragma unroll
    for (int t=0;t<4;t++) acc[s][t]=(f32x4){0.f,0.f,0.f,0.f};
  const short* wp = wT16 + (size_t)m16*H_ + kb*8;
  #pragma unroll
  for (int t=0;t<4;t++){
    bf16x8 b0 = *(const bf16x8*)(wp + (size_t)(t*16)*H_);
    acc[0][t] = __builtin_amdgcn_mfma_f32_16x16x32_bf16(ax0a, b0, acc[0][t], 0,0,0);
    acc[1][t] = __builtin_amdgcn_mfma_f32_16x16x32_bf16(ax0b, b0, acc[1][t], 0,0,0);
    bf16x8 b1 = *(const bf16x8*)(wp + (size_t)(t*16)*H_ + 32);
    acc[0][t] = __builtin_amdgcn_mfma_f32_16x16x32_bf16(ax1a, b1, acc[0][t], 0,0,0);
    acc[1][t] = __builtin_amdgcn_mfma_f32_16x16x32_bf16(ax1b, b1, acc[1][t], 0,0,0);
  }

  int mrow = kb*4;
  float ps[2][4], pd[2][4];
  #pragma unroll
  for (int s=0;s<2;s++)
    #pragma unroll
    for (int q=0;q<4;q++){ ps[s][q]=0.f; pd[s][q]=0.f; }
  #pragma unroll
  for (int t=0;t<4;t++){
    int f = t*16 + m16;
    float as = atts[f], ad = attd[f];
    #pragma unroll
    for (int s=0;s<2;s++){
      #pragma unroll
      for (int q=0;q<4;q++){
        float v = acc[s][t][q];
        sH[w][s*16 + mrow + q][f] = __half_as_ushort(__float2half(v));
        ps[s][q] = fmaf(v, as, ps[s][q]); pd[s][q] = fmaf(v, ad, pd[s][q]);
      }
    }
  }
  // coalesced h16 store phase (wave-local)
  {
    int row = lane >> 1, half = lane & 1;
    int node = n0 + row;
    if (node < N){
      __half* gp = h16 + (size_t)node*H_ + half*32;
      #pragma unroll
      for (int i=0;i<8;i++){
        *(uint2*)(gp + i*4) = *(const uint2*)&sH[w][row][half*32 + i*4];
      }
    }
  }
  #pragma unroll
  for (int d=1; d<16; d<<=1){
    #pragma unroll
    for (int s=0;s<2;s++)
      #pragma unroll
      for (int q=0;q<4;q++){ ps[s][q] += __shfl_xor(ps[s][q], d); pd[s][q] += __shfl_xor(pd[s][q], d); }
  }
  if (m16==0){
    #pragma unroll
    for (int s=0;s<2;s++){
      #pragma unroll
      for (int q=0;q<4;q++){
        int node = n0 + s*16 + mrow + q;
        if (node < N){ ssc[node]=ps[s][q]; dsc[node]=pd[s][q]; }
      }
    }
  }
}

// GAT: 4 nodes/wave, 16 lanes/node. Single-pass safe-exp softmax. offS/offE bounds.
template<int L>
__global__ void __launch_bounds__(256)
k_gat_g4(const __half* __restrict__ h16, const float* __restrict__ ssc,
         const float* __restrict__ dsc, const uint2* __restrict__ rec,
         const int* __restrict__ offS, const int* __restrict__ offE,
         const float* __restrict__ bias, short* __restrict__ hgat16, int N){
  int lane = threadIdx.x & 63, w = threadIdx.x >> 6;
  int g = lane >> 4, fl = lane & 15;
  int node = blockIdx.x*16 + w*4 + g;
  if (node >= N) return;
  int e0 = offS[node], e1 = offE[node];
  float dval = dsc[node];
  float acc0=0.f, acc1=0.f, acc2=0.f, acc3=0.f, den=0.f;
  int gbase = lane & 48;                 // g*16
  for (int base = e0; base < e1; base += 16){
    int p = base + fl;
    float ex = 0.f; int s = 0;
    if (p < e1){
      uint2 r = rec[p];
      s = (int)((r.y & 0xFFFFu) | ((r.x & 1u) << 16));
      unsigned hb = (L==0) ? (r.x & 0xFFFEu) : (L==1) ? (r.x >> 16) : (r.y >> 16);
      float a = ssc[s] + dval + h2f_(hb);
      a = (a > 0.f) ? a : SLOPE*a;
      ex = __expf(a);
    }
    den += ex;
    int cnt = e1 - base; if (cnt > 16) cnt = 16;
    for (int j = 0; j < cnt; j++){
      float exb = __shfl(ex, gbase + j);
      int   sb  = __shfl(s,  gbase + j);
      uint2 hv = *(const uint2*)(h16 + (size_t)sb*H_ + 4*fl);
      float2 f0 = __half22float2(*(__half2*)&hv.x);
      float2 f1 = __half22float2(*(__half2*)&hv.y);
      acc0 = fmaf(exb, f0.x, acc0);
      acc1 = fmaf(exb, f0.y, acc1);
      acc2 = fmaf(exb, f1.x, acc2);
      acc3 = fmaf(exb, f1.y, acc3);
    }
  }
  #pragma unroll
  for (int d=1; d<16; d<<=1) den += __shfl_xor(den, d);
  float4 bv = *(const float4*)(bias + 4*fl);
  float inv = 1.0f/den;
  float v0 = fmaxf(fmaf(acc0,inv,bv.x), 0.f);
  float v1 = fmaxf(fmaf(acc1,inv,bv.y), 0.f);
  float v2 = fmaxf(fmaf(acc2,inv,bv.z), 0.f);
  float v3 = fmaxf(fmaf(acc3,inv,bv.w), 0.f);
  uint2 o;
  o.x = ((unsigned)(unsigned short)f2bf(v1)<<16) | (unsigned short)f2bf(v0);
  o.y = ((unsigned)(unsigned short)f2bf(v3)<<16) | (unsigned short)f2bf(v2);
  *(uint2*)(hgat16 + (size_t)node*H_ + 4*fl) = o;
}

// block per graph: zero-atomic pooled output (batch sorted, xi bf16)
__global__ void __launch_bounds__(256)
k_pool_g(const short* __restrict__ xi, const float* __restrict__ wout,
         const int* __restrict__ gstart, const float* __restrict__ b_out,
         float* __restrict__ out){
  int g = blockIdx.x;
  int a = gstart[g], b = gstart[g+1];
  float acc = 0.f;
  for (int n = a + threadIdx.x; n < b; n += 256){
    const uint4* xr = (const uint4*)(xi + (size_t)n*H_);   // 8 bf16 per uint4
    float s = 0.f;
    #pragma unroll
    for (int q=0;q<8;q++){
      uint4 v = xr[q];
      s += bf2f((unsigned short)(v.x&0xFFFF))*wout[8*q]   + bf2f((unsigned short)(v.x>>16))*wout[8*q+1]
         + bf2f((unsigned short)(v.y&0xFFFF))*wout[8*q+2] + bf2f((unsigned short)(v.y>>16))*wout[8*q+3]
         + bf2f((unsigned short)(v.z&0xFFFF))*wout[8*q+4] + bf2f((unsigned short)(v.z>>16))*wout[8*q+5]
         + bf2f((unsigned short)(v.w&0xFFFF))*wout[8*q+6] + bf2f((unsigned short)(v.w>>16))*wout[8*q+7];
    }
    acc += s;
  }
  #pragma unroll
  for (int d=32; d; d>>=1) acc += __shfl_xor(acc, d);
  __shared__ float sh[4];
  if ((threadIdx.x&63)==0) sh[threadIdx.x>>6] = acc;
  __syncthreads();
  if (threadIdx.x==0) out[g] = sh[0]+sh[1]+sh[2]+sh[3] + b_out[0];
}

extern "C" void kernel_launch(void* const* d_in, const int* in_sizes, int n_in,
                              void* d_out, int out_size, void* d_ws, size_t ws_size,
                              hipStream_t stream){
  const float* x       = (const float*)d_in[0];
  const float* eattr   = (const float*)d_in[1];
  const float* w_node  = (const float*)d_in[2];
  const float* b_node  = (const float*)d_in[3];
  const float* w_edge  = (const float*)d_in[4];
  const float* b_edge  = (const float*)d_in[5];
  const float* conv_W  = (const float*)d_in[6];
  const float* conv_We = (const float*)d_in[7];
  const float* att_s   = (const float*)d_in[8];
  const float* att_d   = (const float*)d_in[9];
  const float* att_e   = (const float*)d_in[10];
  const float* conv_b  = (const float*)d_in[11];
  const float* gWih    = (const float*)d_in[12];
  const float* gWhh    = (const float*)d_in[13];
  const float* gbih    = (const float*)d_in[14];
  const float* gbhh    = (const float*)d_in[15];
  const float* w_out   = (const float*)d_in[16];
  const float* b_out   = (const float*)d_in[17];
  const int*   eidx    = (const int*)d_in[18];
  const int*   batch   = (const int*)d_in[19];
  float* out = (float*)d_out;

  int N = in_sizes[0]/DIN;
  int E = in_sizes[1]/DE;
  int G = out_size;
  const int* src = eidx;
  const int* dst = eidx + E;

  char* p = (char*)d_ws;
  auto carve = [&](size_t bytes)->void*{ void* r=(void*)p; p += (bytes+255)&~(size_t)255; return r; };
  short*  xi0    = (short*)carve((size_t)N*H_*2);
  short*  xi1    = (short*)carve((size_t)N*H_*2);
  __half* h16    = (__half*)carve((size_t)N*H_*2);
  short*  hgat16 = (short*)carve((size_t)N*H_*2);
  float*  ssc    = (float*)carve((size_t)N*4);
  float*  dsc    = (float*)carve((size_t)N*4);
  uint2*  esc8   = (uint2*)carve((size_t)E*8);
  uint2*  rec    = (uint2*)carve((size_t)256*CAP2*8);
  uint2*  bin8   = (uint2*)carve((size_t)256*CAP*8);
  unsigned short* bin2 = (unsigned short*)carve((size_t)256*CAP*2);
  int*    offS   = (int*)carve((size_t)N*4);
  int*    offE   = (int*)carve((size_t)N*4);
  int*    bcur   = (int*)carve((size_t)256*4);
  int*    gstart = (int*)carve((size_t)(G+1)*4);
  short*  wnT16  = (short*)carve((size_t)DIN*H_*2);
  short*  weT16p = (short*)carve((size_t)64*32*2);
  short*  cWT16  = (short*)carve((size_t)3*H_*H_*2);
  short*  WihT16 = (short*)carve((size_t)3*192*H_*2);
  short*  WhhT16 = (short*)carve((size_t)3*192*H_*2);
  float*  ve     = (float*)carve((size_t)3*H_*4);

  auto cdiv=[](int a,int b){return (a+b-1)/b;};
  int NBK = cdiv(N,BNODE);

  int prep_total = 2048+2048+12288+36864+36864+192+256+N;
  k_prep<<<cdiv(prep_total,256),256,0,stream>>>(w_node, w_edge, b_edge, conv_W, gWih, gWhh,
                                                conv_We, att_e, batch,
                                                wnT16, weT16p, cWT16, WihT16, WhhT16, ve,
                                                bcur, gstart, N, G);
  k_nmlp_m<<<cdiv(N,64),256,0,stream>>>(x, wnT16, b_node, xi0, N);
  k_edge_m<<<cdiv(E,128),256,0,stream>>>(eattr, weT16p, ve, src, esc8, E);
  k_binA<<<cdiv(E,ACH),256,0,stream>>>(esc8, dst, bcur, bin8, bin2, E);
  k_binB2<<<NBK,256,0,stream>>>(bin8, bin2, bcur, offS, offE, rec, N);

  int NB128 = cdiv(N,128);
  int NB16  = cdiv(N,16);
  for (int l=0; l<3; l++){
    const short* xin = (l&1) ? xi1 : xi0;
    short*       xo  = (l&1) ? xi0 : xi1;
    k_linh_m<<<NB128,256,0,stream>>>(xin, cWT16 + (size_t)l*H_*H_, att_s + l*H_, att_d + l*H_,
                                     h16, ssc, dsc, N);
    if (l==0)      k_gat_g4<0><<<NB16,256,0,stream>>>(h16, ssc, dsc, rec, offS, offE, conv_b + l*H_, hgat16, N);
    else if (l==1) k_gat_g4<1><<<NB16,256,0,stream>>>(h16, ssc, dsc, rec, offS, offE, conv_b + l*H_, hgat16, N);
    else           k_gat_g4<2><<<NB16,256,0,stream>>>(h16, ssc, dsc, rec, offS, offE, conv_b + l*H_, hgat16, N);
    k_gru_m<<<NB128,256,0,stream>>>(hgat16, xin, xo, WihT16 + (size_t)l*192*H_, WhhT16 + (size_t)l*192*H_,
                                    gbih + l*3*H_, gbhh + l*3*H_, N);
  }

  k_pool_g<<<G,256,0,stream>>>(xi1, w_out, gstart, b_out, out);
}

// Round 25
// 357.618 us; speedup vs baseline: 1.0491x; 1.0491x over previous
//
#include <hip/hip_runtime.h>
#include <hip/hip_fp16.h>

constexpr int H_  = 64;   // hidden
constexpr int DIN = 32;   // atom feature dim
constexpr int DE  = 16;   // edge feature dim
constexpr int BNODE = 512;  // nodes per scatter bucket (dstlocal < 512)
constexpr int ACH   = 2048; // edges per binning chunk
constexpr int CAP   = 6144; // per-bucket bin region capacity (mean 5120 + 14 sigma)
constexpr int CAP2  = CAP + BNODE; // per-bucket rec region (edges + self-loops)
#define SLOPE 0.2f

typedef __attribute__((ext_vector_type(8))) short bf16x8;
typedef __attribute__((ext_vector_type(4))) float f32x4;

__device__ __forceinline__ float sigm_(float x){ return 1.0f/(1.0f+__expf(-x)); }
__device__ __forceinline__ float tanh_(float x){ float e=__expf(2.0f*x); return 1.0f - 2.0f/(e+1.0f); }
__device__ __forceinline__ short f2bf(float f){   // RNE float->bf16
  unsigned u = __float_as_uint(f);
  u += 0x7FFF + ((u>>16)&1);
  return (short)(u>>16);
}
__device__ __forceinline__ float bf2f(unsigned short s){
  return __uint_as_float(((unsigned)s)<<16);
}
__device__ __forceinline__ float h2f_(unsigned hb){
  return __half2float(__ushort_as_half((unsigned short)hb));
}

// mega-kernel: weight prep + bcur init + graph bounds
__global__ void k_prep(const float* __restrict__ w_node, const float* __restrict__ w_edge,
                       const float* __restrict__ b_edge,
                       const float* __restrict__ conv_W, const float* __restrict__ gWih,
                       const float* __restrict__ gWhh, const float* __restrict__ conv_We,
                       const float* __restrict__ att_e, const int* __restrict__ batch,
                       short* __restrict__ wnT16, short* __restrict__ weT16p,
                       short* __restrict__ cWT16, short* __restrict__ WihT16,
                       short* __restrict__ WhhT16, float* __restrict__ ve,
                       int* __restrict__ bcur, int* __restrict__ gstart, int N, int G){
  int id = blockIdx.x*blockDim.x + threadIdx.x;
  if (id < 2048){                                   // wnT16 [64][32]
    int j = id >> 5, k = id & 31;
    wnT16[id] = f2bf(w_node[k*64 + j]);
    return;
  }
  id -= 2048;
  if (id < 2048){                                   // weT16p [64][32]; k=16 row = bias
    int j = id >> 5, k = id & 31;
    weT16p[id] = (k < DE) ? f2bf(w_edge[k*64 + j]) : (k == DE ? f2bf(b_edge[j]) : (short)0);
    return;
  }
  id -= 2048;
  if (id < 12288){                                  // cWT16 [3][64 j][64 k]
    int l = id / 4096, rem = id & 4095, j = rem >> 6, k = rem & 63;
    cWT16[id] = f2bf(conv_W[l*4096 + k*64 + j]);
    return;
  }
  id -= 12288;
  if (id < 36864){                                  // WihT16 [3][192 j][64 k]
    int l = id / 12288, rem = id % 12288, j = rem >> 6, k = rem & 63;
    WihT16[id] = f2bf(gWih[l*12288 + k*192 + j]);
    return;
  }
  id -= 36864;
  if (id < 36864){                                  // WhhT16
    int l = id / 12288, rem = id % 12288, j = rem >> 6, k = rem & 63;
    WhhT16[id] = f2bf(gWhh[l*12288 + k*192 + j]);
    return;
  }
  id -= 36864;
  if (id < 192){                                    // ve[l][k]
    int l = id >> 6, k = id & 63;
    const float* w = conv_We + (size_t)(l*64+k)*64;
    const float* a = att_e + l*64;
    float s = 0.f;
    #pragma unroll
    for (int j=0;j<64;j++) s += w[j]*a[j];
    ve[id] = s;
    return;
  }
  id -= 192;
  if (id < 256){ bcur[id] = id*CAP; return; }       // fixed-capacity bin regions
  id -= 256;
  if (id < N){                                      // graph bounds (sorted batch)
    int b = batch[id];
    int bp = (id==0) ? -1 : batch[id-1];
    for (int g=bp+1; g<=b; g++) gstart[g]=id;
    if (id==N-1){ for (int g=b+1; g<=G; g++) gstart[g]=N; }
  }
}

// MFMA node MLP: xi16 = bf16(relu(x @ w_node + b)), K=32 exact. No LDS.
__global__ void __launch_bounds__(256,4)
k_nmlp_m(const float* __restrict__ x, const short* __restrict__ wT16,
         const float* __restrict__ b, short* __restrict__ xi, int N){
  int lane = threadIdx.x & 63, w = threadIdx.x >> 6;
  int m16 = lane & 15, kb = lane >> 4;
  int n0 = blockIdx.x*64 + w*16;
  int arow = n0 + m16; if (arow > N-1) arow = N-1;
  const float* xr = x + (size_t)arow*DIN + kb*8;
  float4 a0 = *(const float4*)xr, a1 = *(const float4*)(xr+4);
  bf16x8 af;
  af[0]=f2bf(a0.x); af[1]=f2bf(a0.y); af[2]=f2bf(a0.z); af[3]=f2bf(a0.w);
  af[4]=f2bf(a1.x); af[5]=f2bf(a1.y); af[6]=f2bf(a1.z); af[7]=f2bf(a1.w);
  f32x4 acc[4];
  #pragma unroll
  for (int t=0;t<4;t++) acc[t]=(f32x4){0.f,0.f,0.f,0.f};
  const short* wp = wT16 + (size_t)m16*DIN + kb*8;
  #pragma unroll
  for (int t=0;t<4;t++){
    bf16x8 bb = *(const bf16x8*)(wp + (size_t)(t*16)*DIN);
    acc[t] = __builtin_amdgcn_mfma_f32_16x16x32_bf16(af, bb, acc[t], 0,0,0);
  }
  int mrow = (lane>>4)*4;
  #pragma unroll
  for (int t=0;t<4;t++){
    int f = t*16 + m16;
    float bj = b[f];
    #pragma unroll
    for (int q=0;q<4;q++){
      int node = n0 + mrow + q;
      if (node < N) xi[(size_t)node*H_ + f] = f2bf(fmaxf(acc[t][q] + bj, 0.f));
    }
  }
}

// Transposed MFMA edge scores: D = W^T @ attr^T so each lane holds 16 j-values of ONE
// edge -> ve-dot is lane-local; reduce is only over the 4 kb groups (2 shfl steps).
__global__ void __launch_bounds__(256,4)
k_edge_m(const float* __restrict__ attr, const short* __restrict__ weT16p,
         const float* __restrict__ ve, const int* __restrict__ src,
         uint2* __restrict__ esc8, int E){
  int lane = threadIdx.x & 63, w = threadIdx.x >> 6;
  int m16 = lane & 15, kb = lane >> 4;
  int e0 = (blockIdx.x*4 + w)*32;        // 2 tiles of 16 edges
  if (e0 >= E) return;
  const short* wp = weT16p + (size_t)m16*32 + kb*8;
  bf16x8 wA0 = *(const bf16x8*)(wp);
  bf16x8 wA1 = *(const bf16x8*)(wp + 16*32);
  bf16x8 wA2 = *(const bf16x8*)(wp + 32*32);
  bf16x8 wA3 = *(const bf16x8*)(wp + 48*32);
  bf16x8 af0 = {0,0,0,0,0,0,0,0}, af1 = {0,0,0,0,0,0,0,0};
  if (kb < 2){
    int r0 = e0 + m16;      if (r0 > E-1) r0 = E-1;
    int r1 = e0 + 16 + m16; if (r1 > E-1) r1 = E-1;
    const float* ap0 = attr + (size_t)r0*DE + kb*8;
    const float* ap1 = attr + (size_t)r1*DE + kb*8;
    float4 a0 = *(const float4*)ap0, a1 = *(const float4*)(ap0+4);
    float4 b0 = *(const float4*)ap1, b1 = *(const float4*)(ap1+4);
    af0[0]=f2bf(a0.x); af0[1]=f2bf(a0.y); af0[2]=f2bf(a0.z); af0[3]=f2bf(a0.w);
    af0[4]=f2bf(a1.x); af0[5]=f2bf(a1.y); af0[6]=f2bf(a1.z); af0[7]=f2bf(a1.w);
    af1[0]=f2bf(b0.x); af1[1]=f2bf(b0.y); af1[2]=f2bf(b0.z); af1[3]=f2bf(b0.w);
    af1[4]=f2bf(b1.x); af1[5]=f2bf(b1.y); af1[6]=f2bf(b1.z); af1[7]=f2bf(b1.w);
  } else if (kb == 2){
    af0[0] = (short)0x3F80; af1[0] = (short)0x3F80;
  }
  f32x4 accA[4], accB[4];
  #pragma unroll
  for (int t=0;t<4;t++){ accA[t]=(f32x4){0.f,0.f,0.f,0.f}; accB[t]=(f32x4){0.f,0.f,0.f,0.f}; }
  accA[0] = __builtin_amdgcn_mfma_f32_16x16x32_bf16(wA0, af0, accA[0], 0,0,0);
  accB[0] = __builtin_amdgcn_mfma_f32_16x16x32_bf16(wA0, af1, accB[0], 0,0,0);
  accA[1] = __builtin_amdgcn_mfma_f32_16x16x32_bf16(wA1, af0, accA[1], 0,0,0);
  accB[1] = __builtin_amdgcn_mfma_f32_16x16x32_bf16(wA1, af1, accB[1], 0,0,0);
  accA[2] = __builtin_amdgcn_mfma_f32_16x16x32_bf16(wA2, af0, accA[2], 0,0,0);
  accB[2] = __builtin_amdgcn_mfma_f32_16x16x32_bf16(wA2, af1, accB[2], 0,0,0);
  accA[3] = __builtin_amdgcn_mfma_f32_16x16x32_bf16(wA3, af0, accA[3], 0,0,0);
  accB[3] = __builtin_amdgcn_mfma_f32_16x16x32_bf16(wA3, af1, accB[3], 0,0,0);

  int kb4 = kb*4;
  float sA0=0.f,sA1=0.f,sA2=0.f, sB0=0.f,sB1=0.f,sB2=0.f;
  #pragma unroll
  for (int t=0;t<4;t++){
    float4 v0 = *(const float4*)(ve + t*16 + kb4);
    float4 v1 = *(const float4*)(ve + 64 + t*16 + kb4);
    float4 v2 = *(const float4*)(ve + 128 + t*16 + kb4);
    float eA0 = fmaxf(accA[t][0],0.f), eA1 = fmaxf(accA[t][1],0.f);
    float eA2 = fmaxf(accA[t][2],0.f), eA3 = fmaxf(accA[t][3],0.f);
    float eB0 = fmaxf(accB[t][0],0.f), eB1 = fmaxf(accB[t][1],0.f);
    float eB2 = fmaxf(accB[t][2],0.f), eB3 = fmaxf(accB[t][3],0.f);
    sA0 = fmaf(eA0,v0.x, fmaf(eA1,v0.y, fmaf(eA2,v0.z, fmaf(eA3,v0.w, sA0))));
    sA1 = fmaf(eA0,v1.x, fmaf(eA1,v1.y, fmaf(eA2,v1.z, fmaf(eA3,v1.w, sA1))));
    sA2 = fmaf(eA0,v2.x, fmaf(eA1,v2.y, fmaf(eA2,v2.z, fmaf(eA3,v2.w, sA2))));
    sB0 = fmaf(eB0,v0.x, fmaf(eB1,v0.y, fmaf(eB2,v0.z, fmaf(eB3,v0.w, sB0))));
    sB1 = fmaf(eB0,v1.x, fmaf(eB1,v1.y, fmaf(eB2,v1.z, fmaf(eB3,v1.w, sB1))));
    sB2 = fmaf(eB0,v2.x, fmaf(eB1,v2.y, fmaf(eB2,v2.z, fmaf(eB3,v2.w, sB2))));
  }
  sA0 += __shfl_xor(sA0,16); sA0 += __shfl_xor(sA0,32);
  sA1 += __shfl_xor(sA1,16); sA1 += __shfl_xor(sA1,32);
  sA2 += __shfl_xor(sA2,16); sA2 += __shfl_xor(sA2,32);
  sB0 += __shfl_xor(sB0,16); sB0 += __shfl_xor(sB0,32);
  sB1 += __shfl_xor(sB1,16); sB1 += __shfl_xor(sB1,32);
  sB2 += __shfl_xor(sB2,16); sB2 += __shfl_xor(sB2,32);
  if (lane < 16){
    int eA = e0 + lane;
    if (eA < E){
      unsigned sv = (unsigned)src[eA];
      unsigned h0 = (__half_as_ushort(__float2half(sA0)) & 0xFFFEu) | (sv >> 16);
      unsigned h1 = __half_as_ushort(__float2half(sA1));
      unsigned h2 = __half_as_ushort(__float2half(sA2));
      esc8[eA] = make_uint2(h0 | (h1<<16), (sv & 0xFFFFu) | (h2<<16));
    }
    int eB = e0 + 16 + lane;
    if (eB < E){
      unsigned sv = (unsigned)src[eB];
      unsigned h0 = (__half_as_ushort(__float2half(sB0)) & 0xFFFEu) | (sv >> 16);
      unsigned h1 = __half_as_ushort(__float2half(sB1));
      unsigned h2 = __half_as_ushort(__float2half(sB2));
      esc8[eB] = make_uint2(h0 | (h1<<16), (sv & 0xFFFFu) | (h2<<16));
    }
  }
}

// pass A: LDS-binned append of 8B records + 2B dstlocal into fixed per-bucket regions.
__global__ void __launch_bounds__(256)
k_binA(const uint2* __restrict__ esc8, const int* __restrict__ dst,
       int* __restrict__ bcur, uint2* __restrict__ bin8, unsigned short* __restrict__ bin2,
       int E){
  __shared__ int cnt[256];
  __shared__ int ofs[256];
  __shared__ int gofs[256];
  __shared__ uint2 st8[ACH];
  __shared__ unsigned short st2[ACH];
  __shared__ unsigned char sbid[ACH];
  int tid = threadIdx.x;
  int base = blockIdx.x * ACH;
  cnt[tid] = 0;
  __syncthreads();
  uint2 r8[8]; int bb[8]; int ms[8]; int dl[8];
  #pragma unroll
  for (int k=0;k<8;k++){
    int e = base + tid + k*256;
    bb[k] = -1;
    if (e < E){
      r8[k] = esc8[e];
      int d = dst[e];
      bb[k] = d >> 9;
      dl[k] = d & (BNODE-1);
      ms[k] = atomicAdd(&cnt[bb[k]], 1);
    }
  }
  __syncthreads();
  int v = cnt[tid];
  ofs[tid] = v;
  __syncthreads();
  for (int d=1; d<256; d<<=1){
    int t = 0;
    if (tid>=d) t = ofs[tid-d];
    __syncthreads();
    if (tid>=d) ofs[tid] += t;
    __syncthreads();
  }
  int total = ofs[255];
  int excl = ofs[tid] - v;
  __syncthreads();
  ofs[tid] = excl;
  __syncthreads();
  #pragma unroll
  for (int k=0;k<8;k++){
    if (bb[k] >= 0){
      int slot = ofs[bb[k]] + ms[k];
      st8[slot] = r8[k];
      st2[slot] = (unsigned short)dl[k];
      sbid[slot] = (unsigned char)bb[k];
    }
  }
  if (v > 0) gofs[tid] = atomicAdd(&bcur[tid], v);
  __syncthreads();
  for (int slot = tid; slot < total; slot += 256){
    int b = sbid[slot];
    int gp = gofs[b] + (slot - ofs[b]);
    bin8[gp] = st8[slot];
    bin2[gp] = st2[slot];
  }
}

// fused pass B: per bucket = histogram -> LDS scan -> offS/offE -> scatter (+LDS score
// sums) -> self-loop records. Zero global atomics, no global scan kernels.
__global__ void __launch_bounds__(256)
k_binB2(const uint2* __restrict__ bin8, const unsigned short* __restrict__ bin2,
        const int* __restrict__ bcur, int* __restrict__ offS, int* __restrict__ offE,
        uint2* __restrict__ rec, int N){
  __shared__ int lcnt[BNODE];
  __shared__ int lcur[BNODE];
  __shared__ int loffS[BNODE];
  __shared__ int sc[256];
  __shared__ float ls0[BNODE], ls1[BNODE], ls2[BNODE];
  int b = blockIdx.x, tid = threadIdx.x;
  int n0 = b*BNODE;
  int n1 = n0 + BNODE; if (n1 > N) n1 = N;
  int nn = n1 - n0;
  for (int i=tid;i<BNODE;i+=256){ lcnt[i]=0; ls0[i]=0.f; ls1[i]=0.f; ls2[i]=0.f; }
  __syncthreads();
  int beg = b*CAP, cntb = bcur[b] - beg;
  for (int idx=tid; idx<cntb; idx+=256) atomicAdd(&lcnt[bin2[beg+idx]], 1);
  __syncthreads();
  int i0 = 2*tid, i1 = 2*tid+1;
  int a0 = (i0<nn) ? lcnt[i0]+1 : 0;
  int a1 = (i1<nn) ? lcnt[i1]+1 : 0;
  int pair = a0+a1;
  sc[tid] = pair;
  __syncthreads();
  for (int d=1; d<256; d<<=1){
    int t = 0; if (tid>=d) t = sc[tid-d];
    __syncthreads();
    if (tid>=d) sc[tid] += t;
    __syncthreads();
  }
  int excl = sc[tid] - pair;
  int base = b*CAP2;
  if (i0<nn){ int o=base+excl;    offS[n0+i0]=o; offE[n0+i0]=o+a0; loffS[i0]=o; lcur[i0]=o+1; }
  if (i1<nn){ int o=base+excl+a0; offS[n0+i1]=o; offE[n0+i1]=o+a1; loffS[i1]=o; lcur[i1]=o+1; }
  __syncthreads();
  for (int idx=tid; idx<cntb; idx+=256){
    uint2 r = bin8[beg+idx];
    int dl = bin2[beg+idx];
    int p = atomicAdd(&lcur[dl], 1);
    rec[p] = r;
    atomicAdd(&ls0[dl], h2f_(r.x & 0xFFFEu));
    atomicAdd(&ls1[dl], h2f_(r.x >> 16));
    atomicAdd(&ls2[dl], h2f_(r.y >> 16));
  }
  __syncthreads();
  for (int i=tid; i<nn; i+=256){
    int cnt = lcnt[i];
    float inv = (cnt>0) ? 1.0f/(float)cnt : 0.0f;
    unsigned h0 = __half_as_ushort(__float2half(ls0[i]*inv)) & 0xFFFEu;
    unsigned h1 = __half_as_ushort(__float2half(ls1[i]*inv));
    unsigned h2 = __half_as_ushort(__float2half(ls2[i]*inv));
    unsigned s = (unsigned)(n0+i);
    rec[loffS[i]] = make_uint2(h0 | (s>>16) | (h1<<16), (s & 0xFFFFu) | (h2<<16));
  }
}

// MFMA GRU: 2 strips/wave, per-tile epilogue -> only 8 live accumulators.
__global__ void __launch_bounds__(256,4)
k_gru_m(const short* __restrict__ hg16, const short* __restrict__ xin, short* __restrict__ xout,
        const short* __restrict__ WihT16, const short* __restrict__ WhhT16,
        const float* __restrict__ bih, const float* __restrict__ bhh, int N){
  int lane = threadIdx.x & 63, w = threadIdx.x >> 6;
  int m16 = lane & 15;
  int kb  = lane >> 4;
  int n0 = blockIdx.x*128 + w*32;

  int r0 = n0 + m16;      if (r0 > N-1) r0 = N-1;
  int r1 = n0 + 16 + m16; if (r1 > N-1) r1 = N-1;
  const short* h0p = hg16 + (size_t)r0*H_ + kb*8;
  const short* h1p = hg16 + (size_t)r1*H_ + kb*8;
  bf16x8 ah0a = *(const bf16x8*)(h0p), ah1a = *(const bf16x8*)(h0p+32);
  bf16x8 ah0b = *(const bf16x8*)(h1p), ah1b = *(const bf16x8*)(h1p+32);
  const short* x0p = xin + (size_t)r0*H_ + kb*8;
  const short* x1p = xin + (size_t)r1*H_ + kb*8;
  bf16x8 ax0a = *(const bf16x8*)(x0p), ax1a = *(const bf16x8*)(x0p+32);
  bf16x8 ax0b = *(const bf16x8*)(x1p), ax1b = *(const bf16x8*)(x1p+32);

  const short* wi = WihT16 + (size_t)m16*H_ + kb*8;
  const short* wh = WhhT16 + (size_t)m16*H_ + kb*8;
  int mrow = (lane>>4)*4;

  #pragma unroll
  for (int t=0;t<4;t++){
    f32x4 aR0=(f32x4){0.f,0.f,0.f,0.f}, aR1=(f32x4){0.f,0.f,0.f,0.f};
    f32x4 aZ0=(f32x4){0.f,0.f,0.f,0.f}, aZ1=(f32x4){0.f,0.f,0.f,0.f};
    f32x4 aNi0=(f32x4){0.f,0.f,0.f,0.f}, aNi1=(f32x4){0.f,0.f,0.f,0.f};
    f32x4 aNh0=(f32x4){0.f,0.f,0.f,0.f}, aNh1=(f32x4){0.f,0.f,0.f,0.f};
    bf16x8 b;
    b = *(const bf16x8*)(wi + (size_t)(t*16)*H_);
    aR0 = __builtin_amdgcn_mfma_f32_16x16x32_bf16(ah0a, b, aR0, 0,0,0);
    aR1 = __builtin_amdgcn_mfma_f32_16x16x32_bf16(ah0b, b, aR1, 0,0,0);
    b = *(const bf16x8*)(wi + (size_t)(t*16)*H_ + 32);
    aR0 = __builtin_amdgcn_mfma_f32_16x16x32_bf16(ah1a, b, aR0, 0,0,0);
    aR1 = __builtin_amdgcn_mfma_f32_16x16x32_bf16(ah1b, b, aR1, 0,0,0);
    b = *(const bf16x8*)(wh + (size_t)(t*16)*H_);
    aR0 = __builtin_amdgcn_mfma_f32_16x16x32_bf16(ax0a, b, aR0, 0,0,0);
    aR1 = __builtin_amdgcn_mfma_f32_16x16x32_bf16(ax0b, b, aR1, 0,0,0);
    b = *(const bf16x8*)(wh + (size_t)(t*16)*H_ + 32);
    aR0 = __builtin_amdgcn_mfma_f32_16x16x32_bf16(ax1a, b, aR0, 0,0,0);
    aR1 = __builtin_amdgcn_mfma_f32_16x16x32_bf16(ax1b, b, aR1, 0,0,0);

    b = *(const bf16x8*)(wi + (size_t)(64+t*16)*H_);
    aZ0 = __builtin_amdgcn_mfma_f32_16x16x32_bf16(ah0a, b, aZ0, 0,0,0);
    aZ1 = __builtin_amdgcn_mfma_f32_16x16x32_bf16(ah0b, b, aZ1, 0,0,0);
    b = *(const bf16x8*)(wi + (size_t)(64+t*16)*H_ + 32);
    aZ0 = __builtin_amdgcn_mfma_f32_16x16x32_bf16(ah1a, b, aZ0, 0,0,0);
    aZ1 = __builtin_amdgcn_mfma_f32_16x16x32_bf16(ah1b, b, aZ1, 0,0,0);
    b = *(const bf16x8*)(wh + (size_t)(64+t*16)*H_);
    aZ0 = __builtin_amdgcn_mfma_f32_16x16x32_bf16(ax0a, b, aZ0, 0,0,0);
    aZ1 = __builtin_amdgcn_mfma_f32_16x16x32_bf16(ax0b, b, aZ1, 0,0,0);
    b = *(const bf16x8*)(wh + (size_t)(64+t*16)*H_ + 32);
    aZ0 = __builtin_amdgcn_mfma_f32_16x16x32_bf16(ax1a, b, aZ0, 0,0,0);
    aZ1 = __builtin_amdgcn_mfma_f32_16x16x32_bf16(ax1b, b, aZ1, 0,0,0);

    b = *(const bf16x8*)(wi + (size_t)(128+t*16)*H_);
    aNi0 = __builtin_amdgcn_mfma_f32_16x16x32_bf16(ah0a, b, aNi0, 0,0,0);
    aNi1 = __builtin_amdgcn_mfma_f32_16x16x32_bf16(ah0b, b, aNi1, 0,0,0);
    b = *(const bf16x8*)(wi + (size_t)(128+t*16)*H_ + 32);
    aNi0 = __builtin_amdgcn_mfma_f32_16x16x32_bf16(ah1a, b, aNi0, 0,0,0);
    aNi1 = __builtin_amdgcn_mfma_f32_16x16x32_bf16(ah1b, b, aNi1, 0,0,0);
    b = *(const bf16x8*)(wh + (size_t)(128+t*16)*H_);
    aNh0 = __builtin_amdgcn_mfma_f32_16x16x32_bf16(ax0a, b, aNh0, 0,0,0);
    aNh1 = __builtin_amdgcn_mfma_f32_16x16x32_bf16(ax0b, b, aNh1, 0,0,0);
    b = *(const bf16x8*)(wh + (size_t)(128+t*16)*H_ + 32);
    aNh0 = __builtin_amdgcn_mfma_f32_16x16x32_bf16(ax1a, b, aNh0, 0,0,0);
    aNh1 = __builtin_amdgcn_mfma_f32_16x16x32_bf16(ax1b, b, aNh1, 0,0,0);

    int f = t*16 + m16;
    float br = bih[f]     + bhh[f];
    float bz = bih[64+f]  + bhh[64+f];
    float bin= bih[128+f], bhn = bhh[128+f];
    #pragma unroll
    for (int q=0;q<4;q++){
      int node = n0 + mrow + q;
      if (node < N){
        float r  = sigm_(aR0[q] + br);
        float z  = sigm_(aZ0[q] + bz);
        float nn = tanh_(aNi0[q] + bin + r*(aNh0[q] + bhn));
        float xv = bf2f((unsigned short)xin[(size_t)node*H_ + f]);
        xout[(size_t)node*H_ + f] = f2bf(fmaxf((1.f-z)*nn + z*xv, 0.f));
      }
    }
    #pragma unroll
    for (int q=0;q<4;q++){
      int node = n0 + 16 + mrow + q;
      if (node < N){
        float r  = sigm_(aR1[q] + br);
        float z  = sigm_(aZ1[q] + bz);
        float nn = tanh_(aNi1[q] + bin + r*(aNh1[q] + bhn));
        float xv = bf2f((unsigned short)xin[(size_t)node*H_ + f]);
        xout[(size_t)node*H_ + f] = f2bf(fmaxf((1.f-z)*nn + z*xv, 0.f));
      }
    }
  }
}

// MFMA linear-h: 2 node-strips per wave (32 nodes), block = 128 nodes. bf16 input.
__global__ void __launch_bounds__(256,4)
k_linh_m(const short* __restrict__ xi, const short* __restrict__ wT16,
         const float* __restrict__ atts, const float* __restrict__ attd,
         __half* __restrict__ h16, float* __restrict__ ssc, float* __restrict__ dsc, int N){
  int lane = threadIdx.x & 63, w = threadIdx.x >> 6;
  int m16 = lane & 15, kb = lane >> 4;
  int n0 = blockIdx.x*128 + w*32;
  int r0 = n0 + m16;      if (r0 > N-1) r0 = N-1;
  int r1 = n0 + 16 + m16; if (r1 > N-1) r1 = N-1;
  const short* x0p = xi + (size_t)r0*H_ + kb*8;
  const short* x1p = xi + (size_t)r1*H_ + kb*8;
  bf16x8 ax0a = *(const bf16x8*)(x0p), ax1a = *(const bf16x8*)(x0p+32);
  bf16x8 ax0b = *(const bf16x8*)(x1p), ax1b = *(const bf16x8*)(x1p+32);

  f32x4 acc[2][4];
  #pragma unroll
  for (int s=0;s<2;s++)
    #pragma unroll
    for (int t=0;t<4;t++) acc[s][t]=(f32x4){0.f,0.f,0.f,0.f};
  const short* wp = wT16 + (size_t)m16*H_ + kb*8;
  #pragma unroll
  for (int t=0;t<4;t++){
    bf16x8 b0 = *(const bf16x8*)(wp + (size_t)(t*16)*H_);
    acc[0][t] = __builtin_amdgcn_mfma_f32_16x16x32_bf16(ax0a, b0, acc[0][t], 0,0,0);
    acc[1][t] = __builtin_amdgcn_mfma_f32_16x16x32_bf16(ax0b, b0, acc[1][t], 0,0,0);
    bf16x8 b1 = *(const bf16x8*)(wp + (size_t)(t*16)*H_ + 32);
    acc[0][t] = __builtin_amdgcn_mfma_f32_16x16x32_bf16(ax1a, b1, acc[0][t], 0,0,0);
    acc[1][t] = __builtin_amdgcn_mfma_f32_16x16x32_bf16(ax1b, b1, acc[1][t], 0,0,0);
  }

  int mrow = (lane>>4)*4;
  float ps[2][4], pd[2][4];
  #pragma unroll
  for (int s=0;s<2;s++)
    #pragma unroll
    for (int q=0;q<4;q++){ ps[s][q]=0.f; pd[s][q]=0.f; }
  #pragma unroll
  for (int t=0;t<4;t++){
    int f = t*16 + m16;
    float as = atts[f], ad = attd[f];
    #pragma unroll
    for (int s=0;s<2;s++){
      #pragma unroll
      for (int q=0;q<4;q++){
        int node = n0 + s*16 + mrow + q;
        float v = acc[s][t][q];
        if (node < N) h16[(size_t)node*H_ + f] = __float2half(v);
        ps[s][q] = fmaf(v, as, ps[s][q]); pd[s][q] = fmaf(v, ad, pd[s][q]);
      }
    }
  }
  #pragma unroll
  for (int d=1; d<16; d<<=1){
    #pragma unroll
    for (int s=0;s<2;s++)
      #pragma unroll
      for (int q=0;q<4;q++){ ps[s][q] += __shfl_xor(ps[s][q], d); pd[s][q] += __shfl_xor(pd[s][q], d); }
  }
  if (m16==0){
    #pragma unroll
    for (int s=0;s<2;s++){
      #pragma unroll
      for (int q=0;q<4;q++){
        int node = n0 + s*16 + mrow + q;
        if (node < N){ ssc[node]=ps[s][q]; dsc[node]=pd[s][q]; }
      }
    }
  }
}

// GAT: 4 nodes/wave, 16 lanes/node. Single-pass safe-exp softmax. offS/offE bounds.
template<int L>
__global__ void __launch_bounds__(256)
k_gat_g4(const __half* __restrict__ h16, const float* __restrict__ ssc,
         const float* __restrict__ dsc, const uint2* __restrict__ rec,
         const int* __restrict__ offS, const int* __restrict__ offE,
         const float* __restrict__ bias, short* __restrict__ hgat16, int N){
  int lane = threadIdx.x & 63, w = threadIdx.x >> 6;
  int g = lane >> 4, fl = lane & 15;
  int node = blockIdx.x*16 + w*4 + g;
  if (node >= N) return;
  int e0 = offS[node], e1 = offE[node];
  float dval = dsc[node];
  float acc0=0.f, acc1=0.f, acc2=0.f, acc3=0.f, den=0.f;
  int gbase = lane & 48;                 // g*16
  for (int base = e0; base < e1; base += 16){
    int p = base + fl;
    float ex = 0.f; int s = 0;
    if (p < e1){
      uint2 r = rec[p];
      s = (int)((r.y & 0xFFFFu) | ((r.x & 1u) << 16));
      unsigned hb = (L==0) ? (r.x & 0xFFFEu) : (L==1) ? (r.x >> 16) : (r.y >> 16);
      float a = ssc[s] + dval + h2f_(hb);
      a = (a > 0.f) ? a : SLOPE*a;
      ex = __expf(a);
    }
    den += ex;
    int cnt = e1 - base; if (cnt > 16) cnt = 16;
    for (int j = 0; j < cnt; j++){
      float exb = __shfl(ex, gbase + j);
      int   sb  = __shfl(s,  gbase + j);
      uint2 hv = *(const uint2*)(h16 + (size_t)sb*H_ + 4*fl);
      float2 f0 = __half22float2(*(__half2*)&hv.x);
      float2 f1 = __half22float2(*(__half2*)&hv.y);
      acc0 = fmaf(exb, f0.x, acc0);
      acc1 = fmaf(exb, f0.y, acc1);
      acc2 = fmaf(exb, f1.x, acc2);
      acc3 = fmaf(exb, f1.y, acc3);
    }
  }
  #pragma unroll
  for (int d=1; d<16; d<<=1) den += __shfl_xor(den, d);
  float4 bv = *(const float4*)(bias + 4*fl);
  float inv = 1.0f/den;
  float v0 = fmaxf(fmaf(acc0,inv,bv.x), 0.f);
  float v1 = fmaxf(fmaf(acc1,inv,bv.y), 0.f);
  float v2 = fmaxf(fmaf(acc2,inv,bv.z), 0.f);
  float v3 = fmaxf(fmaf(acc3,inv,bv.w), 0.f);
  uint2 o;
  o.x = ((unsigned)(unsigned short)f2bf(v1)<<16) | (unsigned short)f2bf(v0);
  o.y = ((unsigned)(unsigned short)f2bf(v3)<<16) | (unsigned short)f2bf(v2);
  *(uint2*)(hgat16 + (size_t)node*H_ + 4*fl) = o;
}

// block per graph: zero-atomic pooled output (batch sorted, xi bf16)
__global__ void __launch_bounds__(256)
k_pool_g(const short* __restrict__ xi, const float* __restrict__ wout,
         const int* __restrict__ gstart, const float* __restrict__ b_out,
         float* __restrict__ out){
  int g = blockIdx.x;
  int a = gstart[g], b = gstart[g+1];
  float acc = 0.f;
  for (int n = a + threadIdx.x; n < b; n += 256){
    const uint4* xr = (const uint4*)(xi + (size_t)n*H_);   // 8 bf16 per uint4
    float s = 0.f;
    #pragma unroll
    for (int q=0;q<8;q++){
      uint4 v = xr[q];
      s += bf2f((unsigned short)(v.x&0xFFFF))*wout[8*q]   + bf2f((unsigned short)(v.x>>16))*wout[8*q+1]
         + bf2f((unsigned short)(v.y&0xFFFF))*wout[8*q+2] + bf2f((unsigned short)(v.y>>16))*wout[8*q+3]
         + bf2f((unsigned short)(v.z&0xFFFF))*wout[8*q+4] + bf2f((unsigned short)(v.z>>16))*wout[8*q+5]
         + bf2f((unsigned short)(v.w&0xFFFF))*wout[8*q+6] + bf2f((unsigned short)(v.w>>16))*wout[8*q+7];
    }
    acc += s;
  }
  #pragma unroll
  for (int d=32; d; d>>=1) acc += __shfl_xor(acc, d);
  __shared__ float sh[4];
  if ((threadIdx.x&63)==0) sh[threadIdx.x>>6] = acc;
  __syncthreads();
  if (threadIdx.x==0) out[g] = sh[0]+sh[1]+sh[2]+sh[3] + b_out[0];
}

extern "C" void kernel_launch(void* const* d_in, const int* in_sizes, int n_in,
                              void* d_out, int out_size, void* d_ws, size_t ws_size,
                              hipStream_t stream){
  const float* x       = (const float*)d_in[0];
  const float* eattr   = (const float*)d_in[1];
  const float* w_node  = (const float*)d_in[2];
  const float* b_node  = (const float*)d_in[3];
  const float* w_edge  = (const float*)d_in[4];
  const float* b_edge  = (const float*)d_in[5];
  const float* conv_W  = (const float*)d_in[6];
  const float* conv_We = (const float*)d_in[7];
  const float* att_s   = (const float*)d_in[8];
  const float* att_d   = (const float*)d_in[9];
  const float* att_e   = (const float*)d_in[10];
  const float* conv_b  = (const float*)d_in[11];
  const float* gWih    = (const float*)d_in[12];
  const float* gWhh    = (const float*)d_in[13];
  const float* gbih    = (const float*)d_in[14];
  const float* gbhh    = (const float*)d_in[15];
  const float* w_out   = (const float*)d_in[16];
  const float* b_out   = (const float*)d_in[17];
  const int*   eidx    = (const int*)d_in[18];
  const int*   batch   = (const int*)d_in[19];
  float* out = (float*)d_out;

  int N = in_sizes[0]/DIN;
  int E = in_sizes[1]/DE;
  int G = out_size;
  const int* src = eidx;
  const int* dst = eidx + E;

  char* p = (char*)d_ws;
  auto carve = [&](size_t bytes)->void*{ void* r=(void*)p; p += (bytes+255)&~(size_t)255; return r; };
  short*  xi0    = (short*)carve((size_t)N*H_*2);
  short*  xi1    = (short*)carve((size_t)N*H_*2);
  __half* h16    = (__half*)carve((size_t)N*H_*2);
  short*  hgat16 = (short*)carve((size_t)N*H_*2);
  float*  ssc    = (float*)carve((size_t)N*4);
  float*  dsc    = (float*)carve((size_t)N*4);
  uint2*  esc8   = (uint2*)carve((size_t)E*8);
  uint2*  rec    = (uint2*)carve((size_t)256*CAP2*8);
  uint2*  bin8   = (uint2*)carve((size_t)256*CAP*8);
  unsigned short* bin2 = (unsigned short*)carve((size_t)256*CAP*2);
  int*    offS   = (int*)carve((size_t)N*4);
  int*    offE   = (int*)carve((size_t)N*4);
  int*    bcur   = (int*)carve((size_t)256*4);
  int*    gstart = (int*)carve((size_t)(G+1)*4);
  short*  wnT16  = (short*)carve((size_t)DIN*H_*2);
  short*  weT16p = (short*)carve((size_t)64*32*2);
  short*  cWT16  = (short*)carve((size_t)3*H_*H_*2);
  short*  WihT16 = (short*)carve((size_t)3*192*H_*2);
  short*  WhhT16 = (short*)carve((size_t)3*192*H_*2);
  float*  ve     = (float*)carve((size_t)3*H_*4);

  auto cdiv=[](int a,int b){return (a+b-1)/b;};
  int NBK = cdiv(N,BNODE);

  int prep_total = 2048+2048+12288+36864+36864+192+256+N;
  k_prep<<<cdiv(prep_total,256),256,0,stream>>>(w_node, w_edge, b_edge, conv_W, gWih, gWhh,
                                                conv_We, att_e, batch,
                                                wnT16, weT16p, cWT16, WihT16, WhhT16, ve,
                                                bcur, gstart, N, G);
  k_nmlp_m<<<cdiv(N,64),256,0,stream>>>(x, wnT16, b_node, xi0, N);
  k_edge_m<<<cdiv(E,128),256,0,stream>>>(eattr, weT16p, ve, src, esc8, E);
  k_binA<<<cdiv(E,ACH),256,0,stream>>>(esc8, dst, bcur, bin8, bin2, E);
  k_binB2<<<NBK,256,0,stream>>>(bin8, bin2, bcur, offS, offE, rec, N);

  int NB128 = cdiv(N,128);
  int NB16  = cdiv(N,16);
  for (int l=0; l<3; l++){
    const short* xin = (l&1) ? xi1 : xi0;
    short*       xo  = (l&1) ? xi0 : xi1;
    k_linh_m<<<NB128,256,0,stream>>>(xin, cWT16 + (size_t)l*H_*H_, att_s + l*H_, att_d + l*H_,
                                     h16, ssc, dsc, N);
    if (l==0)      k_gat_g4<0><<<NB16,256,0,stream>>>(h16, ssc, dsc, rec, offS, offE, conv_b + l*H_, hgat16, N);
    else if (l==1) k_gat_g4<1><<<NB16,256,0,stream>>>(h16, ssc, dsc, rec, offS, offE, conv_b + l*H_, hgat16, N);
    else           k_gat_g4<2><<<NB16,256,0,stream>>>(h16, ssc, dsc, rec, offS, offE, conv_b + l*H_, hgat16, N);
    k_gru_m<<<NB128,256,0,stream>>>(hgat16, xin, xo, WihT16 + (size_t)l*192*H_, WhhT16 + (size_t)l*192*H_,
                                    gbih + l*3*H_, gbhh + l*3*H_, N);
  }

  k_pool_g<<<G,256,0,stream>>>(xi1, w_out, gstart, b_out, out);
}